// Round 1
// baseline (377.174 us; speedup 1.0000x reference)
//
#include <hip/hip_runtime.h>
#include <stdint.h>

typedef __attribute__((ext_vector_type(4))) float f32x4;
typedef __attribute__((ext_vector_type(8))) short s16x8;

struct Params {
  const float* cls_feat[3];
  const float* reg_feat[3];
  const float* obj_w[3];
  const float* obj_b[3];
  const float* cls_w[3];
  const float* cls_b[3];
  const float* reg_w[3];
  const float* reg_b[3];
  float* out;
};

__device__ __forceinline__ unsigned short f2bf(float f) {
  unsigned int u = __builtin_bit_cast(unsigned int, f);
  u = (u + 0x7FFFu + ((u >> 16) & 1u)) >> 16;  // RNE
  return (unsigned short)u;
}

#define LDS_PITCH 264  // 256 + 8 pad (shorts); 528B row -> 8 distinct 16B chunk slots

__global__ __launch_bounds__(320) void head_kernel(Params p) {
  const int tid  = threadIdx.x;
  const int lane = tid & 63;
  const int wave = tid >> 6;      // 0..4, one 16-row o-tile each
  const int quad = lane >> 4;     // 0..3
  const int col  = lane & 15;
  const bool is_cls = (blockIdx.y == 0);

  // block -> (batch, level, m-tile). 132 tiles/batch: 100 + 25 + 7
  int bx = blockIdx.x;
  int b  = bx / 132;
  int t  = bx - b * 132;
  int level, tloc;
  if (t < 100)      { level = 0; tloc = t; }
  else if (t < 125) { level = 1; tloc = t - 100; }
  else              { level = 2; tloc = t - 125; }

  const int   LW_[3]   = {80, 40, 20};
  const int   LM_[3]   = {6400, 1600, 400};
  const float LS_[3]   = {8.f, 16.f, 32.f};
  const int   LOFF_[3] = {0, 6400, 8000};

  const int   Mlvl = LM_[level];
  const int   Moff = LOFF_[level];
  const float strd = LS_[level];
  const int   m0   = tloc * 64;
  int valid = Mlvl - m0; if (valid > 64) valid = 64;

  __shared__ __align__(16) short lds_feat[64 * LDS_PITCH];  // 33792 B, bf16 [m][k]
  __shared__ float g_lds[4][64];                            // DFL expectations

  // ---- stage features: coalesced along m, transpose via per-thread k-gather ----
  const float* featp = (is_cls ? p.cls_feat[level] : p.reg_feat[level])
                       + (size_t)b * 256 * (size_t)Mlvl;
  {
    const int mloc = tid & 63;
    int mg = m0 + mloc; if (mg > Mlvl - 1) mg = Mlvl - 1;  // clamp partial tile
    const float* colp = featp + mg;
    for (int cb = wave; cb < 32; cb += 5) {
      const int c0 = cb * 8;
      float f[8];
      #pragma unroll
      for (int j = 0; j < 8; ++j) f[j] = colp[(size_t)(c0 + j) * Mlvl];
      s16x8 h;
      #pragma unroll
      for (int j = 0; j < 8; ++j) h[j] = (short)f2bf(f[j]);
      *(s16x8*)&lds_feat[mloc * LDS_PITCH + c0] = h;
    }
  }

  // ---- A-frag preload (weights, fp32 -> bf16 on the fly) ----
  // A[o=lane&15][k=quad*8+j], full K=256 = 8 frags
  s16x8 afrag[8];
  {
    const int orow = wave * 16 + col;
    const float* wptr = nullptr;
    if (is_cls) {
      wptr = p.cls_w[level] + orow * 256;
    } else {
      if (orow < 64)       wptr = p.reg_w[level] + orow * 256;
      else if (orow == 64) wptr = p.obj_w[level];
      // rows 65..79: zero pad
    }
    #pragma unroll
    for (int s = 0; s < 8; ++s) {
      s16x8 a = {0, 0, 0, 0, 0, 0, 0, 0};
      if (wptr) {
        const f32x4* wp = (const f32x4*)(wptr + s * 32 + quad * 8);
        f32x4 w0 = wp[0], w1 = wp[1];
        a[0] = (short)f2bf(w0[0]); a[1] = (short)f2bf(w0[1]);
        a[2] = (short)f2bf(w0[2]); a[3] = (short)f2bf(w0[3]);
        a[4] = (short)f2bf(w1[0]); a[5] = (short)f2bf(w1[1]);
        a[6] = (short)f2bf(w1[2]); a[7] = (short)f2bf(w1[3]);
      }
      afrag[s] = a;
    }
  }

  // bias for the 4 accumulator rows this lane owns: o = wave*16 + quad*4 + r
  float bias[4];
  #pragma unroll
  for (int r = 0; r < 4; ++r) {
    const int o = wave * 16 + quad * 4 + r;
    if (is_cls) bias[r] = p.cls_b[level][o];
    else        bias[r] = (o < 64) ? p.reg_b[level][o]
                        : ((o == 64) ? p.obj_b[level][0] : 0.f);
  }

  __syncthreads();

  // ---- GEMM: D[o][m] = W[o][k] * feat[k][m], K=256 ----
  f32x4 acc[4];
  #pragma unroll
  for (int mf = 0; mf < 4; ++mf) {
    f32x4 d = {0.f, 0.f, 0.f, 0.f};
    const short* brow = &lds_feat[(mf * 16 + col) * LDS_PITCH + quad * 8];
    #pragma unroll
    for (int s = 0; s < 8; ++s) {
      s16x8 bfrag = *(const s16x8*)(brow + s * 32);
      d = __builtin_amdgcn_mfma_f32_16x16x32_bf16(afrag[s], bfrag, d, 0, 0, 0);
    }
    acc[mf] = d;
  }

  // ---- epilogue ----
  const size_t outbase = (size_t)b * 8400 + Moff + m0;
  float* out = p.out;

  if (is_cls) {
    #pragma unroll
    for (int mf = 0; mf < 4; ++mf) {
      const int m = mf * 16 + col;
      if (m < valid) {
        const size_t rowp = (outbase + m) * 149 + 1 + wave * 16 + quad * 4;
        #pragma unroll
        for (int r = 0; r < 4; ++r) out[rowp + r] = acc[mf][r] + bias[r];
      }
    }
  } else if (wave < 4) {
    // reg logits (ch 81..144) + DFL expectation for group f = wave
    const float projscale = 16.f / 15.f;
    #pragma unroll
    for (int mf = 0; mf < 4; ++mf) {
      const int m = mf * 16 + col;
      const float v0 = acc[mf][0] + bias[0];
      const float v1 = acc[mf][1] + bias[1];
      const float v2 = acc[mf][2] + bias[2];
      const float v3 = acc[mf][3] + bias[3];
      if (m < valid) {
        const size_t rowp = (outbase + m) * 149 + 81 + wave * 16 + quad * 4;
        out[rowp + 0] = v0; out[rowp + 1] = v1;
        out[rowp + 2] = v2; out[rowp + 3] = v3;
      }
      // softmax over 16 bins: 4 regs x 4 quads (same m column)
      float mx = fmaxf(fmaxf(v0, v1), fmaxf(v2, v3));
      mx = fmaxf(mx, __shfl_xor(mx, 16, 64));
      mx = fmaxf(mx, __shfl_xor(mx, 32, 64));
      const float e0 = __expf(v0 - mx), e1 = __expf(v1 - mx);
      const float e2 = __expf(v2 - mx), e3 = __expf(v3 - mx);
      float s = e0 + e1 + e2 + e3;
      const float q4 = (float)(quad * 4);
      float n = q4 * e0 + (q4 + 1.f) * e1 + (q4 + 2.f) * e2 + (q4 + 3.f) * e3;
      s += __shfl_xor(s, 16, 64); s += __shfl_xor(s, 32, 64);
      n += __shfl_xor(n, 16, 64); n += __shfl_xor(n, 32, 64);
      if (quad == 0) g_lds[wave][m] = projscale * n / s;
    }
  } else {
    // wave 4: obj row (o=64 -> quad 0, reg 0)
    #pragma unroll
    for (int mf = 0; mf < 4; ++mf) {
      const int m = mf * 16 + col;
      if (quad == 0 && m < valid)
        out[(outbase + m) * 149] = acc[mf][0] + bias[0];
    }
  }

  __syncthreads();

  // box decode (reg blocks, wave 4): anchors +/- expectation * stride
  if (!is_cls && wave == 4) {
    const int m = lane;
    if (m < valid) {
      const float g0 = g_lds[0][m], g1 = g_lds[1][m];
      const float g2 = g_lds[2][m], g3 = g_lds[3][m];
      const int mg = m0 + m;
      int hh;
      if (level == 0)      hh = mg / 80;
      else if (level == 1) hh = mg / 40;
      else                 hh = mg / 20;
      const int ww = mg - hh * LW_[level];
      const float ax = (ww + 0.5f) * strd;
      const float ay = (hh + 0.5f) * strd;
      const size_t rowp = (outbase + m) * 149 + 145;
      out[rowp + 0] = ax - g0 * strd;
      out[rowp + 1] = ay - g1 * strd;
      out[rowp + 2] = ax + g2 * strd;
      out[rowp + 3] = ay + g3 * strd;
    }
  }
}

extern "C" void kernel_launch(void* const* d_in, const int* in_sizes, int n_in,
                              void* d_out, int out_size, void* d_ws, size_t ws_size,
                              hipStream_t stream) {
  (void)in_sizes; (void)n_in; (void)out_size; (void)d_ws; (void)ws_size;
  Params p;
  p.cls_feat[0] = (const float*)d_in[0];
  p.reg_feat[0] = (const float*)d_in[1];
  p.cls_feat[1] = (const float*)d_in[2];
  p.reg_feat[1] = (const float*)d_in[3];
  p.cls_feat[2] = (const float*)d_in[4];
  p.reg_feat[2] = (const float*)d_in[5];
  for (int l = 0; l < 3; ++l) {
    const int base = 6 + l * 6;
    p.obj_w[l] = (const float*)d_in[base + 0];
    p.obj_b[l] = (const float*)d_in[base + 1];
    p.cls_w[l] = (const float*)d_in[base + 2];
    p.cls_b[l] = (const float*)d_in[base + 3];
    p.reg_w[l] = (const float*)d_in[base + 4];
    p.reg_b[l] = (const float*)d_in[base + 5];
  }
  p.out = (float*)d_out;

  dim3 grid(16 * 132, 2);  // x: batch*tile, y: 0=cls GEMM, 1=reg/obj GEMM
  dim3 block(320);         // 5 waves, one 16-row o-tile each
  hipLaunchKernelGGL(head_kernel, grid, block, 0, stream, p);
}